// Round 1
// baseline (8893.946 us; speedup 1.0000x reference)
//
#include <hip/hip_runtime.h>
#include <hip/hip_bf16.h>

// Persistent-LSTM design:
//   B=64,S=512,D=256,H=512. 4 teams x 16 batches; team = 64 WGs x 128 thr (2 waves).
//   Wave owns 4 h-indices (16 gate rows), holds W (hi+lo bf16) in 192 VGPRs for all steps.
//   gates = [x_t, h_{t-1}] @ W^T via mfma_f32_16x16x32_bf16, A=W rows, B=batches.
//   C/D layout (col=lane&15=batch, row=quad*4+reg) => lane holds i,f,g,o for one
//   (batch, h-idx) in acc[0..3]; LSTM cell is lane-local.
//   Step sync: per-WG flags (window-checked vs MAGIC for 0xAA-poison safety) +
//   double-buffered bf16 hi/lo h planes in d_ws; release-fence(agent) producer,
//   relaxed-agent sc1 polls/loads consumer. No LDS, no cooperative launch needed
//   (256 WGs, 1/CU, trivially co-resident).

#define NB 64
#define NS 512
#define ND 256
#define NH 512
#define FLAG_MAGIC 0x41000000

typedef __bf16 bf16x8 __attribute__((ext_vector_type(8)));
typedef float  f32x4  __attribute__((ext_vector_type(4)));

union Frag {
  bf16x8 v;
  unsigned long long u[2];
  __bf16 e[8];
};

__device__ __forceinline__ float bf2f(__bf16 b) {
  unsigned short us = __builtin_bit_cast(unsigned short, b);
  unsigned int ui = ((unsigned int)us) << 16;
  return __builtin_bit_cast(float, ui);
}

// split x into bf16 hi + bf16 lo (RNE), x ~= hi + lo to ~2^-17 rel
__device__ __forceinline__ void hilo8(const float* vals, Frag& fh, Frag& fl) {
#pragma unroll
  for (int j = 0; j < 8; ++j) {
    __bf16 hi = (__bf16)vals[j];
    float r = vals[j] - bf2f(hi);
    fh.e[j] = hi;
    fl.e[j] = (__bf16)r;
  }
}

__device__ __forceinline__ float fsigmoid(float x) {
  return 1.0f / (1.0f + __expf(-x));
}
__device__ __forceinline__ float ftanh(float x) {
  float t = fminf(fmaxf(2.0f * x, -30.0f), 30.0f);  // clamp: no inf/inf NaN
  float e = __expf(t);
  return (e - 1.0f) / (e + 1.0f);
}

__global__ __launch_bounds__(128, 1)
void lstm_persistent(const float* __restrict__ x,     // [B,S,D]
                     const float* __restrict__ Wih,   // [4H,D]
                     const float* __restrict__ Whh,   // [4H,H]
                     const float* __restrict__ bih,   // [4H]
                     const float* __restrict__ bhh,   // [4H]
                     const float* __restrict__ h0,    // [B,H]
                     const float* __restrict__ c0,    // [B,H]
                     float* __restrict__ out,         // [B*S*H + B*H + B*H]
                     int* __restrict__ flags,         // [4][64] in d_ws
                     unsigned short* __restrict__ hplane,  // [2][B][H] bf16-hi
                     unsigned short* __restrict__ lplane)  // [2][B][H] bf16-lo
{
  const int tid  = threadIdx.x;
  const int lane = tid & 63;
  const int wv   = tid >> 6;              // wave 0/1 in WG
  const int team = blockIdx.x >> 6;       // 0..3  (16 batches each)
  const int wg   = blockIdx.x & 63;       // 0..63 (8 h-indices each)
  const int l15  = lane & 15;
  const int quad = lane >> 4;             // 0..3
  const int hb   = wg * 8 + wv * 4;       // wave's h-index base
  const int myb  = team * 16 + l15;       // this lane's batch (B-frag n / C col)
  const int myh  = hb + quad;             // this lane's h-index (C rows j=quad)

  int* flagsT = flags + team * 64;
  if (tid == 0)
    __hip_atomic_store(flagsT + wg, FLAG_MAGIC, __ATOMIC_RELAXED,
                       __HIP_MEMORY_SCOPE_AGENT);

  // ---- persistent A operand: W rows, compensated hi/lo --------------------
  // A-frag: lane holds row m = lane&15, k = quad*8+j. m -> (j=m>>2, g=m&3).
  const int jA = l15 >> 2;
  const int gA = l15 & 3;
  const int rA = gA * NH + hb + jA;       // gate-row in [0,2048)
  bf16x8 Ahi[24], Alo[24];
  {
    const float* wi = Wih + rA * ND;
    const float* wh = Whh + rA * NH;
#pragma unroll
    for (int c = 0; c < 24; ++c) {
      int k0 = c * 32 + quad * 8;
      const float* src = (c < 8) ? (wi + k0) : (wh + (k0 - 256));
      float4 f0 = *(const float4*)(src);
      float4 f1 = *(const float4*)(src + 4);
      float vals[8] = {f0.x, f0.y, f0.z, f0.w, f1.x, f1.y, f1.z, f1.w};
      Frag fh, fl;
      hilo8(vals, fh, fl);
      Ahi[c] = fh.v;
      Alo[c] = fl.v;
    }
  }

  // biases for this lane's 4 gates (C layout: reg g <-> row m=quad*4+g)
  float bias[4];
#pragma unroll
  for (int g = 0; g < 4; ++g)
    bias[g] = bih[g * NH + myh] + bhh[g * NH + myh];

  float c_st  = c0[myb * NH + myh];
  float h_val = 0.0f;

  const int planeHalf = NB * NH;

#pragma unroll 1
  for (int t = 0; t < NS; ++t) {
    // ---- issue x loads before the poll (hide spin latency) ----------------
    float4 xf[16];
    const float* xr = x + (myb * NS + t) * ND + quad * 8;
#pragma unroll
    for (int c = 0; c < 8; ++c) {
      xf[2 * c]     = *(const float4*)(xr + 32 * c);
      xf[2 * c + 1] = *(const float4*)(xr + 32 * c + 4);
    }

    f32x4 a_hh = {bias[0], bias[1], bias[2], bias[3]};
    f32x4 a_hl = {0.f, 0.f, 0.f, 0.f};
    f32x4 a_lh = {0.f, 0.f, 0.f, 0.f};

    // ---- x-projection MFMAs (no h dependency) -----------------------------
#pragma unroll
    for (int c = 0; c < 8; ++c) {
      float vals[8] = {xf[2*c].x, xf[2*c].y, xf[2*c].z, xf[2*c].w,
                       xf[2*c+1].x, xf[2*c+1].y, xf[2*c+1].z, xf[2*c+1].w};
      Frag bh, bl;
      hilo8(vals, bh, bl);
      a_hh = __builtin_amdgcn_mfma_f32_16x16x32_bf16(Ahi[c], bh.v, a_hh, 0, 0, 0);
      a_hl = __builtin_amdgcn_mfma_f32_16x16x32_bf16(Ahi[c], bl.v, a_hl, 0, 0, 0);
      a_lh = __builtin_amdgcn_mfma_f32_16x16x32_bf16(Alo[c], bh.v, a_lh, 0, 0, 0);
    }

    // ---- recurrent part ---------------------------------------------------
    if (t > 0) {
      // wait until all 64 team WGs finished step t-1 (flag >= MAGIC+t).
      // window check vs MAGIC guards against 0xAA poison / garbage in d_ws.
      while (true) {
        int fl = __hip_atomic_load(flagsT + lane, __ATOMIC_RELAXED,
                                   __HIP_MEMORY_SCOPE_AGENT);
        unsigned int d = (unsigned int)(fl - FLAG_MAGIC);
        if (__all(d >= (unsigned int)t && d <= 512u)) break;
        __builtin_amdgcn_s_sleep(1);
      }
      asm volatile("" ::: "memory");  // no h load hoisted above the poll

      const int par = (t + 1) & 1;    // parity of t-1
      const unsigned short* hbp = hplane + par * planeHalf + myb * NH + quad * 8;
      const unsigned short* lbp = lplane + par * planeHalf + myb * NH + quad * 8;
#pragma unroll
      for (int c = 8; c < 24; ++c) {
        int off = 32 * (c - 8);
        Frag bh, bl;
        bh.u[0] = __hip_atomic_load((const unsigned long long*)(hbp + off),
                                    __ATOMIC_RELAXED, __HIP_MEMORY_SCOPE_AGENT);
        bh.u[1] = __hip_atomic_load((const unsigned long long*)(hbp + off + 4),
                                    __ATOMIC_RELAXED, __HIP_MEMORY_SCOPE_AGENT);
        bl.u[0] = __hip_atomic_load((const unsigned long long*)(lbp + off),
                                    __ATOMIC_RELAXED, __HIP_MEMORY_SCOPE_AGENT);
        bl.u[1] = __hip_atomic_load((const unsigned long long*)(lbp + off + 4),
                                    __ATOMIC_RELAXED, __HIP_MEMORY_SCOPE_AGENT);
        a_hh = __builtin_amdgcn_mfma_f32_16x16x32_bf16(Ahi[c], bh.v, a_hh, 0, 0, 0);
        a_hl = __builtin_amdgcn_mfma_f32_16x16x32_bf16(Ahi[c], bl.v, a_hl, 0, 0, 0);
        a_lh = __builtin_amdgcn_mfma_f32_16x16x32_bf16(Alo[c], bh.v, a_lh, 0, 0, 0);
      }
    } else {
      // t == 0: h comes from the h0 input (fp32, pristine)
      const float* hr = h0 + myb * NH + quad * 8;
#pragma unroll
      for (int c = 8; c < 24; ++c) {
        int off = 32 * (c - 8);
        float4 f0 = *(const float4*)(hr + off);
        float4 f1 = *(const float4*)(hr + off + 4);
        float vals[8] = {f0.x, f0.y, f0.z, f0.w, f1.x, f1.y, f1.z, f1.w};
        Frag bh, bl;
        hilo8(vals, bh, bl);
        a_hh = __builtin_amdgcn_mfma_f32_16x16x32_bf16(Ahi[c], bh.v, a_hh, 0, 0, 0);
        a_hl = __builtin_amdgcn_mfma_f32_16x16x32_bf16(Ahi[c], bl.v, a_hl, 0, 0, 0);
        a_lh = __builtin_amdgcn_mfma_f32_16x16x32_bf16(Alo[c], bh.v, a_lh, 0, 0, 0);
      }
    }

    // ---- LSTM cell (fully lane-local thanks to C-layout choice) -----------
    float pre_i = a_hh[0] + a_hl[0] + a_lh[0];
    float pre_f = a_hh[1] + a_hl[1] + a_lh[1];
    float pre_g = a_hh[2] + a_hl[2] + a_lh[2];
    float pre_o = a_hh[3] + a_hl[3] + a_lh[3];
    float gi = fsigmoid(pre_i);
    float gf = fsigmoid(pre_f);
    float gg = ftanh(pre_g);
    float go = fsigmoid(pre_o);
    c_st  = gf * c_st + gi * gg;
    h_val = go * ftanh(c_st);

    // embeddings output (also serves as the journal of h_t)
    out[(myb * NS + t) * NH + myh] = h_val;

    // publish h_t as bf16 hi/lo; pack adjacent h-index pair into one u32 store
    __bf16 hh = (__bf16)h_val;
    float  rr = h_val - bf2f(hh);
    __bf16 hl = (__bf16)rr;
    unsigned int uh = (unsigned int)__builtin_bit_cast(unsigned short, hh);
    unsigned int ul = (unsigned int)__builtin_bit_cast(unsigned short, hl);
    unsigned int ph = (unsigned int)__shfl_xor((int)uh, 16, 64);  // quad^1 partner
    unsigned int pl = (unsigned int)__shfl_xor((int)ul, 16, 64);
    if ((quad & 1) == 0) {
      int par  = t & 1;
      int eoff = par * planeHalf + myb * NH + myh;  // myh even -> 4B aligned
      *(unsigned int*)(hplane + eoff) = uh | (ph << 16);
      *(unsigned int*)(lplane + eoff) = ul | (pl << 16);
    }

    // release: flush h stores to the coherence point, then raise our flag.
    // (release-only fence: wbl2 without invalidate, keeps x cached in L2)
    __builtin_amdgcn_fence(__ATOMIC_RELEASE, "agent");
    __syncthreads();
    if (tid == 0)
      __hip_atomic_store(flagsT + wg, FLAG_MAGIC + t + 1, __ATOMIC_RELAXED,
                         __HIP_MEMORY_SCOPE_AGENT);
  }

  // hT, cT tails
  const int obase = NB * NS * NH;
  out[obase + myb * NH + myh] = h_val;
  out[obase + NB * NH + myb * NH + myh] = c_st;
}

extern "C" void kernel_launch(void* const* d_in, const int* in_sizes, int n_in,
                              void* d_out, int out_size, void* d_ws, size_t ws_size,
                              hipStream_t stream) {
  const float* x   = (const float*)d_in[0];
  const float* Wih = (const float*)d_in[1];
  const float* Whh = (const float*)d_in[2];
  const float* bih = (const float*)d_in[3];
  const float* bhh = (const float*)d_in[4];
  const float* h0  = (const float*)d_in[5];
  const float* c0  = (const float*)d_in[6];
  float* out = (float*)d_out;

  char* ws = (char*)d_ws;
  int* flags = (int*)ws;                                   // 4*64*4 = 1 KiB
  unsigned short* hplane = (unsigned short*)(ws + 1024);   // 2*64*512*2 = 128 KiB
  unsigned short* lplane = (unsigned short*)(ws + 1024 + 2 * NB * NH * 2);
  // total d_ws footprint: ~257 KiB

  lstm_persistent<<<dim3(256), dim3(128), 0, stream>>>(
      x, Wih, Whh, bih, bhh, h0, c0, out, flags, hplane, lplane);
}

// Round 2
// 5245.128 us; speedup vs baseline: 1.6957x; 1.6957x over previous
//
#include <hip/hip_runtime.h>
#include <hip/hip_bf16.h>

// Persistent-LSTM design:
//   B=64,S=512,D=256,H=512. 4 teams x 16 batches; team = 64 WGs x 128 thr (2 waves).
//   Wave owns 4 h-indices (16 gate rows), holds W (hi+lo bf16) in 192 VGPRs for all steps.
//   gates = [x_t, h_{t-1}] @ W^T via mfma_f32_16x16x32_bf16, A=W rows, B=batches.
//   C/D layout (col=lane&15=batch, row=quad*4+reg) => lane holds i,f,g,o for one
//   (batch, h-idx) in acc[0..3]; LSTM cell is lane-local.
//
//   Step sync (ROUND 2 CHANGE): h hi/lo planes are published with RELAXED
//   AGENT-scope atomic stores (global_store sc1 -> write-through to Infinity
//   Cache, the agent coherence point), ordered before the flag by a raw
//   s_waitcnt vmcnt(0). Round 1 used fence(release,"agent"), which emits
//   buffer_wbl2 (full dirty-L2 writeback) in EVERY WG EVERY STEP -> 131k L2
//   flushes -> 17.4 us/step with all pipes <2% busy. out stores stay plain
//   cached (only read after kernel end). Consumer h/flag loads are sc1 atomics,
//   so no acquire-side buffer_inv needed.

#define NB 64
#define NS 512
#define ND 256
#define NH 512
#define FLAG_MAGIC 0x41000000

typedef __bf16 bf16x8 __attribute__((ext_vector_type(8)));
typedef float  f32x4  __attribute__((ext_vector_type(4)));

union Frag {
  bf16x8 v;
  unsigned long long u[2];
  __bf16 e[8];
};

__device__ __forceinline__ float bf2f(__bf16 b) {
  unsigned short us = __builtin_bit_cast(unsigned short, b);
  unsigned int ui = ((unsigned int)us) << 16;
  return __builtin_bit_cast(float, ui);
}

// split x into bf16 hi + bf16 lo (RNE), x ~= hi + lo to ~2^-17 rel
__device__ __forceinline__ void hilo8(const float* vals, Frag& fh, Frag& fl) {
#pragma unroll
  for (int j = 0; j < 8; ++j) {
    __bf16 hi = (__bf16)vals[j];
    float r = vals[j] - bf2f(hi);
    fh.e[j] = hi;
    fl.e[j] = (__bf16)r;
  }
}

__device__ __forceinline__ float fsigmoid(float x) {
  return 1.0f / (1.0f + __expf(-x));
}
__device__ __forceinline__ float ftanh(float x) {
  float t = fminf(fmaxf(2.0f * x, -30.0f), 30.0f);  // clamp: no inf/inf NaN
  float e = __expf(t);
  return (e - 1.0f) / (e + 1.0f);
}

__global__ __launch_bounds__(128, 1)
void lstm_persistent(const float* __restrict__ x,     // [B,S,D]
                     const float* __restrict__ Wih,   // [4H,D]
                     const float* __restrict__ Whh,   // [4H,H]
                     const float* __restrict__ bih,   // [4H]
                     const float* __restrict__ bhh,   // [4H]
                     const float* __restrict__ h0,    // [B,H]
                     const float* __restrict__ c0,    // [B,H]
                     float* __restrict__ out,         // [B*S*H + B*H + B*H]
                     int* __restrict__ flags,         // [4][64] in d_ws
                     unsigned short* __restrict__ hplane,  // [2][B][H] bf16-hi
                     unsigned short* __restrict__ lplane)  // [2][B][H] bf16-lo
{
  const int tid  = threadIdx.x;
  const int lane = tid & 63;
  const int wv   = tid >> 6;              // wave 0/1 in WG
  const int team = blockIdx.x >> 6;       // 0..3  (16 batches each)
  const int wg   = blockIdx.x & 63;       // 0..63 (8 h-indices each)
  const int l15  = lane & 15;
  const int quad = lane >> 4;             // 0..3
  const int hb   = wg * 8 + wv * 4;       // wave's h-index base
  const int myb  = team * 16 + l15;       // this lane's batch (B-frag n / C col)
  const int myh  = hb + quad;             // this lane's h-index (C rows j=quad)

  int* flagsT = flags + team * 64;
  if (tid == 0)
    __hip_atomic_store(flagsT + wg, FLAG_MAGIC, __ATOMIC_RELAXED,
                       __HIP_MEMORY_SCOPE_AGENT);

  // ---- persistent A operand: W rows, compensated hi/lo --------------------
  // A-frag: lane holds row m = lane&15, k = quad*8+j. m -> (j=m>>2, g=m&3).
  const int jA = l15 >> 2;
  const int gA = l15 & 3;
  const int rA = gA * NH + hb + jA;       // gate-row in [0,2048)
  bf16x8 Ahi[24], Alo[24];
  {
    const float* wi = Wih + rA * ND;
    const float* wh = Whh + rA * NH;
#pragma unroll
    for (int c = 0; c < 24; ++c) {
      int k0 = c * 32 + quad * 8;
      const float* src = (c < 8) ? (wi + k0) : (wh + (k0 - 256));
      float4 f0 = *(const float4*)(src);
      float4 f1 = *(const float4*)(src + 4);
      float vals[8] = {f0.x, f0.y, f0.z, f0.w, f1.x, f1.y, f1.z, f1.w};
      Frag fh, fl;
      hilo8(vals, fh, fl);
      Ahi[c] = fh.v;
      Alo[c] = fl.v;
    }
  }

  // biases for this lane's 4 gates (C layout: reg g <-> row m=quad*4+g)
  float bias[4];
#pragma unroll
  for (int g = 0; g < 4; ++g)
    bias[g] = bih[g * NH + myh] + bhh[g * NH + myh];

  float c_st  = c0[myb * NH + myh];
  float h_val = 0.0f;

  const int planeHalf = NB * NH;

#pragma unroll 1
  for (int t = 0; t < NS; ++t) {
    // ---- issue x loads before the poll (hide spin latency) ----------------
    float4 xf[16];
    const float* xr = x + (myb * NS + t) * ND + quad * 8;
#pragma unroll
    for (int c = 0; c < 8; ++c) {
      xf[2 * c]     = *(const float4*)(xr + 32 * c);
      xf[2 * c + 1] = *(const float4*)(xr + 32 * c + 4);
    }

    f32x4 a_hh = {bias[0], bias[1], bias[2], bias[3]};
    f32x4 a_hl = {0.f, 0.f, 0.f, 0.f};
    f32x4 a_lh = {0.f, 0.f, 0.f, 0.f};

    // ---- x-projection MFMAs (no h dependency) -----------------------------
#pragma unroll
    for (int c = 0; c < 8; ++c) {
      float vals[8] = {xf[2*c].x, xf[2*c].y, xf[2*c].z, xf[2*c].w,
                       xf[2*c+1].x, xf[2*c+1].y, xf[2*c+1].z, xf[2*c+1].w};
      Frag bh, bl;
      hilo8(vals, bh, bl);
      a_hh = __builtin_amdgcn_mfma_f32_16x16x32_bf16(Ahi[c], bh.v, a_hh, 0, 0, 0);
      a_hl = __builtin_amdgcn_mfma_f32_16x16x32_bf16(Ahi[c], bl.v, a_hl, 0, 0, 0);
      a_lh = __builtin_amdgcn_mfma_f32_16x16x32_bf16(Alo[c], bh.v, a_lh, 0, 0, 0);
    }

    // ---- recurrent part ---------------------------------------------------
    if (t > 0) {
      // wait until all 64 team WGs finished step t-1 (flag >= MAGIC+t).
      // window check vs MAGIC guards against 0xAA poison / garbage in d_ws.
      while (true) {
        int fl = __hip_atomic_load(flagsT + lane, __ATOMIC_RELAXED,
                                   __HIP_MEMORY_SCOPE_AGENT);
        unsigned int d = (unsigned int)(fl - FLAG_MAGIC);
        if (__all(d >= (unsigned int)t && d <= 512u)) break;
        __builtin_amdgcn_s_sleep(1);
      }
      asm volatile("" ::: "memory");  // no h load hoisted above the poll

      const int par = (t + 1) & 1;    // parity of t-1
      const unsigned short* hbp = hplane + par * planeHalf + myb * NH + quad * 8;
      const unsigned short* lbp = lplane + par * planeHalf + myb * NH + quad * 8;
#pragma unroll
      for (int c = 8; c < 24; ++c) {
        int off = 32 * (c - 8);
        Frag bh, bl;
        bh.u[0] = __hip_atomic_load((const unsigned long long*)(hbp + off),
                                    __ATOMIC_RELAXED, __HIP_MEMORY_SCOPE_AGENT);
        bh.u[1] = __hip_atomic_load((const unsigned long long*)(hbp + off + 4),
                                    __ATOMIC_RELAXED, __HIP_MEMORY_SCOPE_AGENT);
        bl.u[0] = __hip_atomic_load((const unsigned long long*)(lbp + off),
                                    __ATOMIC_RELAXED, __HIP_MEMORY_SCOPE_AGENT);
        bl.u[1] = __hip_atomic_load((const unsigned long long*)(lbp + off + 4),
                                    __ATOMIC_RELAXED, __HIP_MEMORY_SCOPE_AGENT);
        a_hh = __builtin_amdgcn_mfma_f32_16x16x32_bf16(Ahi[c], bh.v, a_hh, 0, 0, 0);
        a_hl = __builtin_amdgcn_mfma_f32_16x16x32_bf16(Ahi[c], bl.v, a_hl, 0, 0, 0);
        a_lh = __builtin_amdgcn_mfma_f32_16x16x32_bf16(Alo[c], bh.v, a_lh, 0, 0, 0);
      }
    } else {
      // t == 0: h comes from the h0 input (fp32, pristine)
      const float* hr = h0 + myb * NH + quad * 8;
#pragma unroll
      for (int c = 8; c < 24; ++c) {
        int off = 32 * (c - 8);
        float4 f0 = *(const float4*)(hr + off);
        float4 f1 = *(const float4*)(hr + off + 4);
        float vals[8] = {f0.x, f0.y, f0.z, f0.w, f1.x, f1.y, f1.z, f1.w};
        Frag bh, bl;
        hilo8(vals, bh, bl);
        a_hh = __builtin_amdgcn_mfma_f32_16x16x32_bf16(Ahi[c], bh.v, a_hh, 0, 0, 0);
        a_hl = __builtin_amdgcn_mfma_f32_16x16x32_bf16(Ahi[c], bl.v, a_hl, 0, 0, 0);
        a_lh = __builtin_amdgcn_mfma_f32_16x16x32_bf16(Alo[c], bh.v, a_lh, 0, 0, 0);
      }
    }

    // ---- LSTM cell (fully lane-local thanks to C-layout choice) -----------
    float pre_i = a_hh[0] + a_hl[0] + a_lh[0];
    float pre_f = a_hh[1] + a_hl[1] + a_lh[1];
    float pre_g = a_hh[2] + a_hl[2] + a_lh[2];
    float pre_o = a_hh[3] + a_hl[3] + a_lh[3];
    float gi = fsigmoid(pre_i);
    float gf = fsigmoid(pre_f);
    float gg = ftanh(pre_g);
    float go = fsigmoid(pre_o);
    c_st  = gf * c_st + gi * gg;
    h_val = go * ftanh(c_st);

    // embeddings output (plain cached store; only read after kernel end)
    out[(myb * NS + t) * NH + myh] = h_val;

    // publish h_t as bf16 hi/lo; pack adjacent h-index pair into one u32, and
    // store with RELAXED AGENT atomics -> global_store sc1 (write-through to
    // Infinity Cache). This is what lets us drop the wbl2-emitting fence.
    __bf16 hh = (__bf16)h_val;
    float  rr = h_val - bf2f(hh);
    __bf16 hl = (__bf16)rr;
    unsigned int uh = (unsigned int)__builtin_bit_cast(unsigned short, hh);
    unsigned int ul = (unsigned int)__builtin_bit_cast(unsigned short, hl);
    unsigned int ph = (unsigned int)__shfl_xor((int)uh, 16, 64);  // quad^1 partner
    unsigned int pl = (unsigned int)__shfl_xor((int)ul, 16, 64);
    if ((quad & 1) == 0) {
      int par  = t & 1;
      int eoff = par * planeHalf + myb * NH + myh;  // myh even -> 4B aligned
      __hip_atomic_store((unsigned int*)(hplane + eoff), uh | (ph << 16),
                         __ATOMIC_RELAXED, __HIP_MEMORY_SCOPE_AGENT);
      __hip_atomic_store((unsigned int*)(lplane + eoff), ul | (pl << 16),
                         __ATOMIC_RELAXED, __HIP_MEMORY_SCOPE_AGENT);
    }

    // Order the sc1 h stores before the flag WITHOUT buffer_wbl2: the stores
    // are already targeted at the coherence point, so draining vmcnt suffices.
    asm volatile("s_waitcnt vmcnt(0)" ::: "memory");
    __syncthreads();
    if (tid == 0)
      __hip_atomic_store(flagsT + wg, FLAG_MAGIC + t + 1, __ATOMIC_RELAXED,
                         __HIP_MEMORY_SCOPE_AGENT);
  }

  // hT, cT tails
  const int obase = NB * NS * NH;
  out[obase + myb * NH + myh] = h_val;
  out[obase + NB * NH + myb * NH + myh] = c_st;
}

extern "C" void kernel_launch(void* const* d_in, const int* in_sizes, int n_in,
                              void* d_out, int out_size, void* d_ws, size_t ws_size,
                              hipStream_t stream) {
  const float* x   = (const float*)d_in[0];
  const float* Wih = (const float*)d_in[1];
  const float* Whh = (const float*)d_in[2];
  const float* bih = (const float*)d_in[3];
  const float* bhh = (const float*)d_in[4];
  const float* h0  = (const float*)d_in[5];
  const float* c0  = (const float*)d_in[6];
  float* out = (float*)d_out;

  char* ws = (char*)d_ws;
  int* flags = (int*)ws;                                   // 4*64*4 = 1 KiB
  unsigned short* hplane = (unsigned short*)(ws + 1024);   // 2*64*512*2 = 128 KiB
  unsigned short* lplane = (unsigned short*)(ws + 1024 + 2 * NB * NH * 2);
  // total d_ws footprint: ~257 KiB

  lstm_persistent<<<dim3(256), dim3(128), 0, stream>>>(
      x, Wih, Whh, bih, bhh, h0, c0, out, flags, hplane, lplane);
}

// Round 3
// 4603.566 us; speedup vs baseline: 1.9320x; 1.1394x over previous
//
#include <hip/hip_runtime.h>
#include <hip/hip_bf16.h>

// Persistent-LSTM design:
//   B=64,S=512,D=256,H=512. 4 teams x 16 batches; team = 64 WGs x 128 thr (2 waves).
//   Wave owns 4 h-indices (16 gate rows), holds W (hi+lo bf16) in regs for all steps.
//   gates = [x_t, h_{t-1}] @ W^T via mfma_f32_16x16x32_bf16, A=W rows, B=batches.
//   C/D layout (col=lane&15=batch, row=quad*4+reg) => lane-local LSTM cell.
//
//   ROUND 3 CHANGE: h-exchange through a 512-deep RING of hi/lo planes in d_ws
//   (67 MB) instead of a 2-deep parity buffer. Producer sc1 write-through as
//   before, but consumers now use PLAIN CACHED dwordx4 loads: ring addresses
//   are never reused, so no consumer cache can hold a stale copy -> no fences,
//   no buffer_inv, and the ~16 team-waves per XCD share one L2 fill. Round-2's
//   sc1 consumer loads forced the full 16.8 MB/step broadcast through the
//   Infinity Cache (8B scattered atomics) = the dominant per-step cost.
//   Also: `out` store moved AFTER the flag store (its cold-line RFO was inside
//   the per-step vmcnt(0) drain). Fallback to the round-2 kernel if ws_size
//   can't hold the ring.

#define NB 64
#define NS 512
#define ND 256
#define NH 512
#define FLAG_MAGIC 0x41000000
#define PLANE_ELEMS (NB * NH)   // 32768 elements, 64 KiB per plane

typedef __bf16 bf16x8 __attribute__((ext_vector_type(8)));
typedef float  f32x4  __attribute__((ext_vector_type(4)));

union Frag {
  bf16x8 v;
  unsigned long long u[2];
  __bf16 e[8];
};

__device__ __forceinline__ float bf2f(__bf16 b) {
  unsigned short us = __builtin_bit_cast(unsigned short, b);
  unsigned int ui = ((unsigned int)us) << 16;
  return __builtin_bit_cast(float, ui);
}

__device__ __forceinline__ void hilo8(const float* vals, Frag& fh, Frag& fl) {
#pragma unroll
  for (int j = 0; j < 8; ++j) {
    __bf16 hi = (__bf16)vals[j];
    float r = vals[j] - bf2f(hi);
    fh.e[j] = hi;
    fl.e[j] = (__bf16)r;
  }
}

__device__ __forceinline__ float fsigmoid(float x) {
  return 1.0f / (1.0f + __expf(-x));
}
__device__ __forceinline__ float ftanh(float x) {
  float t = fminf(fmaxf(2.0f * x, -30.0f), 30.0f);
  float e = __expf(t);
  return (e - 1.0f) / (e + 1.0f);
}

// ---------------------------------------------------------------------------
// Ring-buffer variant (preferred)
// ---------------------------------------------------------------------------
__global__ __launch_bounds__(128, 1)
void lstm_ring(const float* __restrict__ x,
               const float* __restrict__ Wih,
               const float* __restrict__ Whh,
               const float* __restrict__ bih,
               const float* __restrict__ bhh,
               const float* __restrict__ h0,
               const float* __restrict__ c0,
               float* __restrict__ out,
               int* __restrict__ flags,
               unsigned short* __restrict__ hring,   // [S][B][H] bf16-hi
               unsigned short* __restrict__ lring)   // [S][B][H] bf16-lo
{
  const int tid  = threadIdx.x;
  const int lane = tid & 63;
  const int wv   = tid >> 6;
  const int team = blockIdx.x >> 6;
  const int wg   = blockIdx.x & 63;
  const int l15  = lane & 15;
  const int quad = lane >> 4;
  const int hb   = wg * 8 + wv * 4;
  const int myb  = team * 16 + l15;
  const int myh  = hb + quad;

  int* flagsT = flags + team * 64;
  if (tid == 0)
    __hip_atomic_store(flagsT + wg, FLAG_MAGIC, __ATOMIC_RELAXED,
                       __HIP_MEMORY_SCOPE_AGENT);

  // persistent A operand: W rows, compensated hi/lo
  const int jA = l15 >> 2;
  const int gA = l15 & 3;
  const int rA = gA * NH + hb + jA;
  bf16x8 Ahi[24], Alo[24];
  {
    const float* wi = Wih + rA * ND;
    const float* wh = Whh + rA * NH;
#pragma unroll
    for (int c = 0; c < 24; ++c) {
      int k0 = c * 32 + quad * 8;
      const float* src = (c < 8) ? (wi + k0) : (wh + (k0 - 256));
      float4 f0 = *(const float4*)(src);
      float4 f1 = *(const float4*)(src + 4);
      float vals[8] = {f0.x, f0.y, f0.z, f0.w, f1.x, f1.y, f1.z, f1.w};
      Frag fh, fl;
      hilo8(vals, fh, fl);
      Ahi[c] = fh.v;
      Alo[c] = fl.v;
    }
  }

  float bias[4];
#pragma unroll
  for (int g = 0; g < 4; ++g)
    bias[g] = bih[g * NH + myh] + bhh[g * NH + myh];

  float c_st  = c0[myb * NH + myh];
  float h_val = 0.0f;

#pragma unroll 1
  for (int t = 0; t < NS; ++t) {
    // x loads issued before the poll (hide spin latency)
    float4 xf[16];
    const float* xr = x + (myb * NS + t) * ND + quad * 8;
#pragma unroll
    for (int c = 0; c < 8; ++c) {
      xf[2 * c]     = *(const float4*)(xr + 32 * c);
      xf[2 * c + 1] = *(const float4*)(xr + 32 * c + 4);
    }

    f32x4 a_hh = {bias[0], bias[1], bias[2], bias[3]};
    f32x4 a_hl = {0.f, 0.f, 0.f, 0.f};
    f32x4 a_lh = {0.f, 0.f, 0.f, 0.f};

    // x-projection MFMAs (no h dependency; off the critical path)
#pragma unroll
    for (int c = 0; c < 8; ++c) {
      float vals[8] = {xf[2*c].x, xf[2*c].y, xf[2*c].z, xf[2*c].w,
                       xf[2*c+1].x, xf[2*c+1].y, xf[2*c+1].z, xf[2*c+1].w};
      Frag bh, bl;
      hilo8(vals, bh, bl);
      a_hh = __builtin_amdgcn_mfma_f32_16x16x32_bf16(Ahi[c], bh.v, a_hh, 0, 0, 0);
      a_hl = __builtin_amdgcn_mfma_f32_16x16x32_bf16(Ahi[c], bl.v, a_hl, 0, 0, 0);
      a_lh = __builtin_amdgcn_mfma_f32_16x16x32_bf16(Alo[c], bh.v, a_lh, 0, 0, 0);
    }

    if (t > 0) {
      // wait for all 64 team WGs to finish step t-1
      while (true) {
        int fl = __hip_atomic_load(flagsT + lane, __ATOMIC_RELAXED,
                                   __HIP_MEMORY_SCOPE_AGENT);
        unsigned int d = (unsigned int)(fl - FLAG_MAGIC);
        if (__all(d >= (unsigned int)t && d <= 512u)) break;
        __builtin_amdgcn_s_sleep(1);
      }
      asm volatile("" ::: "memory");  // no h load hoisted above the poll

      // PLAIN cached loads from plane t-1: addresses never previously
      // accessed -> no stale-copy hazard; XCD-mates share the L2 fill.
      const unsigned short* hbp = hring + (t - 1) * PLANE_ELEMS + myb * NH + quad * 8;
      const unsigned short* lbp = lring + (t - 1) * PLANE_ELEMS + myb * NH + quad * 8;
#pragma unroll
      for (int c = 8; c < 24; ++c) {
        int off = 32 * (c - 8);
        Frag bh, bl;
        bh.v = *(const bf16x8*)(hbp + off);   // global_load_dwordx4
        bl.v = *(const bf16x8*)(lbp + off);
        a_hh = __builtin_amdgcn_mfma_f32_16x16x32_bf16(Ahi[c], bh.v, a_hh, 0, 0, 0);
        a_hl = __builtin_amdgcn_mfma_f32_16x16x32_bf16(Ahi[c], bl.v, a_hl, 0, 0, 0);
        a_lh = __builtin_amdgcn_mfma_f32_16x16x32_bf16(Alo[c], bh.v, a_lh, 0, 0, 0);
      }
    } else {
      const float* hr = h0 + myb * NH + quad * 8;
#pragma unroll
      for (int c = 8; c < 24; ++c) {
        int off = 32 * (c - 8);
        float4 f0 = *(const float4*)(hr + off);
        float4 f1 = *(const float4*)(hr + off + 4);
        float vals[8] = {f0.x, f0.y, f0.z, f0.w, f1.x, f1.y, f1.z, f1.w};
        Frag bh, bl;
        hilo8(vals, bh, bl);
        a_hh = __builtin_amdgcn_mfma_f32_16x16x32_bf16(Ahi[c], bh.v, a_hh, 0, 0, 0);
        a_hl = __builtin_amdgcn_mfma_f32_16x16x32_bf16(Ahi[c], bl.v, a_hl, 0, 0, 0);
        a_lh = __builtin_amdgcn_mfma_f32_16x16x32_bf16(Alo[c], bh.v, a_lh, 0, 0, 0);
      }
    }

    // LSTM cell (lane-local)
    float pre_i = a_hh[0] + a_hl[0] + a_lh[0];
    float pre_f = a_hh[1] + a_hl[1] + a_lh[1];
    float pre_g = a_hh[2] + a_hl[2] + a_lh[2];
    float pre_o = a_hh[3] + a_hl[3] + a_lh[3];
    float gi = fsigmoid(pre_i);
    float gf = fsigmoid(pre_f);
    float gg = ftanh(pre_g);
    float go = fsigmoid(pre_o);
    c_st  = gf * c_st + gi * gg;
    h_val = go * ftanh(c_st);

    // publish h_t (sc1 write-through to L3; packed u32 per h-pair)
    __bf16 hh = (__bf16)h_val;
    float  rr = h_val - bf2f(hh);
    __bf16 hl = (__bf16)rr;
    unsigned int uh = (unsigned int)__builtin_bit_cast(unsigned short, hh);
    unsigned int ul = (unsigned int)__builtin_bit_cast(unsigned short, hl);
    unsigned int ph = (unsigned int)__shfl_xor((int)uh, 16, 64);
    unsigned int pl = (unsigned int)__shfl_xor((int)ul, 16, 64);
    if ((quad & 1) == 0) {
      int eoff = t * PLANE_ELEMS + myb * NH + myh;  // myh even -> 4B aligned
      __hip_atomic_store((unsigned int*)(hring + eoff), uh | (ph << 16),
                         __ATOMIC_RELAXED, __HIP_MEMORY_SCOPE_AGENT);
      __hip_atomic_store((unsigned int*)(lring + eoff), ul | (pl << 16),
                         __ATOMIC_RELAXED, __HIP_MEMORY_SCOPE_AGENT);
    }

    // order sc1 h stores before the flag (no wbl2 needed)
    asm volatile("s_waitcnt vmcnt(0)" ::: "memory");
    __syncthreads();
    if (tid == 0)
      __hip_atomic_store(flagsT + wg, FLAG_MAGIC + t + 1, __ATOMIC_RELAXED,
                         __HIP_MEMORY_SCOPE_AGENT);

    // embeddings store AFTER the flag: its cold-line RFO latency is now off
    // the critical path (drained by next iteration's vmcnt(0), ~µs later).
    out[(myb * NS + t) * NH + myh] = h_val;
  }

  const int obase = NB * NS * NH;
  out[obase + myb * NH + myh] = h_val;
  out[obase + NB * NH + myb * NH + myh] = c_st;
}

// ---------------------------------------------------------------------------
// Fallback: exact round-2 kernel (2-deep parity planes, sc1 consumer loads)
// ---------------------------------------------------------------------------
__global__ __launch_bounds__(128, 1)
void lstm_persistent(const float* __restrict__ x,
                     const float* __restrict__ Wih,
                     const float* __restrict__ Whh,
                     const float* __restrict__ bih,
                     const float* __restrict__ bhh,
                     const float* __restrict__ h0,
                     const float* __restrict__ c0,
                     float* __restrict__ out,
                     int* __restrict__ flags,
                     unsigned short* __restrict__ hplane,
                     unsigned short* __restrict__ lplane)
{
  const int tid  = threadIdx.x;
  const int lane = tid & 63;
  const int wv   = tid >> 6;
  const int team = blockIdx.x >> 6;
  const int wg   = blockIdx.x & 63;
  const int l15  = lane & 15;
  const int quad = lane >> 4;
  const int hb   = wg * 8 + wv * 4;
  const int myb  = team * 16 + l15;
  const int myh  = hb + quad;

  int* flagsT = flags + team * 64;
  if (tid == 0)
    __hip_atomic_store(flagsT + wg, FLAG_MAGIC, __ATOMIC_RELAXED,
                       __HIP_MEMORY_SCOPE_AGENT);

  const int jA = l15 >> 2;
  const int gA = l15 & 3;
  const int rA = gA * NH + hb + jA;
  bf16x8 Ahi[24], Alo[24];
  {
    const float* wi = Wih + rA * ND;
    const float* wh = Whh + rA * NH;
#pragma unroll
    for (int c = 0; c < 24; ++c) {
      int k0 = c * 32 + quad * 8;
      const float* src = (c < 8) ? (wi + k0) : (wh + (k0 - 256));
      float4 f0 = *(const float4*)(src);
      float4 f1 = *(const float4*)(src + 4);
      float vals[8] = {f0.x, f0.y, f0.z, f0.w, f1.x, f1.y, f1.z, f1.w};
      Frag fh, fl;
      hilo8(vals, fh, fl);
      Ahi[c] = fh.v;
      Alo[c] = fl.v;
    }
  }

  float bias[4];
#pragma unroll
  for (int g = 0; g < 4; ++g)
    bias[g] = bih[g * NH + myh] + bhh[g * NH + myh];

  float c_st  = c0[myb * NH + myh];
  float h_val = 0.0f;
  const int planeHalf = NB * NH;

#pragma unroll 1
  for (int t = 0; t < NS; ++t) {
    float4 xf[16];
    const float* xr = x + (myb * NS + t) * ND + quad * 8;
#pragma unroll
    for (int c = 0; c < 8; ++c) {
      xf[2 * c]     = *(const float4*)(xr + 32 * c);
      xf[2 * c + 1] = *(const float4*)(xr + 32 * c + 4);
    }

    f32x4 a_hh = {bias[0], bias[1], bias[2], bias[3]};
    f32x4 a_hl = {0.f, 0.f, 0.f, 0.f};
    f32x4 a_lh = {0.f, 0.f, 0.f, 0.f};

#pragma unroll
    for (int c = 0; c < 8; ++c) {
      float vals[8] = {xf[2*c].x, xf[2*c].y, xf[2*c].z, xf[2*c].w,
                       xf[2*c+1].x, xf[2*c+1].y, xf[2*c+1].z, xf[2*c+1].w};
      Frag bh, bl;
      hilo8(vals, bh, bl);
      a_hh = __builtin_amdgcn_mfma_f32_16x16x32_bf16(Ahi[c], bh.v, a_hh, 0, 0, 0);
      a_hl = __builtin_amdgcn_mfma_f32_16x16x32_bf16(Ahi[c], bl.v, a_hl, 0, 0, 0);
      a_lh = __builtin_amdgcn_mfma_f32_16x16x32_bf16(Alo[c], bh.v, a_lh, 0, 0, 0);
    }

    if (t > 0) {
      while (true) {
        int fl = __hip_atomic_load(flagsT + lane, __ATOMIC_RELAXED,
                                   __HIP_MEMORY_SCOPE_AGENT);
        unsigned int d = (unsigned int)(fl - FLAG_MAGIC);
        if (__all(d >= (unsigned int)t && d <= 512u)) break;
        __builtin_amdgcn_s_sleep(1);
      }
      asm volatile("" ::: "memory");

      const int par = (t + 1) & 1;
      const unsigned short* hbp = hplane + par * planeHalf + myb * NH + quad * 8;
      const unsigned short* lbp = lplane + par * planeHalf + myb * NH + quad * 8;
#pragma unroll
      for (int c = 8; c < 24; ++c) {
        int off = 32 * (c - 8);
        Frag bh, bl;
        bh.u[0] = __hip_atomic_load((const unsigned long long*)(hbp + off),
                                    __ATOMIC_RELAXED, __HIP_MEMORY_SCOPE_AGENT);
        bh.u[1] = __hip_atomic_load((const unsigned long long*)(hbp + off + 4),
                                    __ATOMIC_RELAXED, __HIP_MEMORY_SCOPE_AGENT);
        bl.u[0] = __hip_atomic_load((const unsigned long long*)(lbp + off),
                                    __ATOMIC_RELAXED, __HIP_MEMORY_SCOPE_AGENT);
        bl.u[1] = __hip_atomic_load((const unsigned long long*)(lbp + off + 4),
                                    __ATOMIC_RELAXED, __HIP_MEMORY_SCOPE_AGENT);
        a_hh = __builtin_amdgcn_mfma_f32_16x16x32_bf16(Ahi[c], bh.v, a_hh, 0, 0, 0);
        a_hl = __builtin_amdgcn_mfma_f32_16x16x32_bf16(Ahi[c], bl.v, a_hl, 0, 0, 0);
        a_lh = __builtin_amdgcn_mfma_f32_16x16x32_bf16(Alo[c], bh.v, a_lh, 0, 0, 0);
      }
    } else {
      const float* hr = h0 + myb * NH + quad * 8;
#pragma unroll
      for (int c = 8; c < 24; ++c) {
        int off = 32 * (c - 8);
        float4 f0 = *(const float4*)(hr + off);
        float4 f1 = *(const float4*)(hr + off + 4);
        float vals[8] = {f0.x, f0.y, f0.z, f0.w, f1.x, f1.y, f1.z, f1.w};
        Frag bh, bl;
        hilo8(vals, bh, bl);
        a_hh = __builtin_amdgcn_mfma_f32_16x16x32_bf16(Ahi[c], bh.v, a_hh, 0, 0, 0);
        a_hl = __builtin_amdgcn_mfma_f32_16x16x32_bf16(Ahi[c], bl.v, a_hl, 0, 0, 0);
        a_lh = __builtin_amdgcn_mfma_f32_16x16x32_bf16(Alo[c], bh.v, a_lh, 0, 0, 0);
      }
    }

    float pre_i = a_hh[0] + a_hl[0] + a_lh[0];
    float pre_f = a_hh[1] + a_hl[1] + a_lh[1];
    float pre_g = a_hh[2] + a_hl[2] + a_lh[2];
    float pre_o = a_hh[3] + a_hl[3] + a_lh[3];
    float gi = fsigmoid(pre_i);
    float gf = fsigmoid(pre_f);
    float gg = ftanh(pre_g);
    float go = fsigmoid(pre_o);
    c_st  = gf * c_st + gi * gg;
    h_val = go * ftanh(c_st);

    out[(myb * NS + t) * NH + myh] = h_val;

    __bf16 hh = (__bf16)h_val;
    float  rr = h_val - bf2f(hh);
    __bf16 hl = (__bf16)rr;
    unsigned int uh = (unsigned int)__builtin_bit_cast(unsigned short, hh);
    unsigned int ul = (unsigned int)__builtin_bit_cast(unsigned short, hl);
    unsigned int ph = (unsigned int)__shfl_xor((int)uh, 16, 64);
    unsigned int pl = (unsigned int)__shfl_xor((int)ul, 16, 64);
    if ((quad & 1) == 0) {
      int par  = t & 1;
      int eoff = par * planeHalf + myb * NH + myh;
      __hip_atomic_store((unsigned int*)(hplane + eoff), uh | (ph << 16),
                         __ATOMIC_RELAXED, __HIP_MEMORY_SCOPE_AGENT);
      __hip_atomic_store((unsigned int*)(lplane + eoff), ul | (pl << 16),
                         __ATOMIC_RELAXED, __HIP_MEMORY_SCOPE_AGENT);
    }

    asm volatile("s_waitcnt vmcnt(0)" ::: "memory");
    __syncthreads();
    if (tid == 0)
      __hip_atomic_store(flagsT + wg, FLAG_MAGIC + t + 1, __ATOMIC_RELAXED,
                         __HIP_MEMORY_SCOPE_AGENT);
  }

  const int obase = NB * NS * NH;
  out[obase + myb * NH + myh] = h_val;
  out[obase + NB * NH + myb * NH + myh] = c_st;
}

extern "C" void kernel_launch(void* const* d_in, const int* in_sizes, int n_in,
                              void* d_out, int out_size, void* d_ws, size_t ws_size,
                              hipStream_t stream) {
  const float* x   = (const float*)d_in[0];
  const float* Wih = (const float*)d_in[1];
  const float* Whh = (const float*)d_in[2];
  const float* bih = (const float*)d_in[3];
  const float* bhh = (const float*)d_in[4];
  const float* h0  = (const float*)d_in[5];
  const float* c0  = (const float*)d_in[6];
  float* out = (float*)d_out;

  char* ws = (char*)d_ws;
  int* flags = (int*)ws;  // 4*64*4 = 1 KiB, rings/planes at +4096

  const size_t ringBytes = (size_t)NS * PLANE_ELEMS * sizeof(unsigned short);  // 33.5 MB
  const size_t need = 4096 + 2 * ringBytes;  // ~67.1 MB

  if (ws_size >= need) {
    unsigned short* hring = (unsigned short*)(ws + 4096);
    unsigned short* lring = (unsigned short*)(ws + 4096 + ringBytes);
    lstm_ring<<<dim3(256), dim3(128), 0, stream>>>(
        x, Wih, Whh, bih, bhh, h0, c0, out, flags, hring, lring);
  } else {
    unsigned short* hplane = (unsigned short*)(ws + 4096);
    unsigned short* lplane = (unsigned short*)(ws + 4096 + 2 * NB * NH * 2);
    lstm_persistent<<<dim3(256), dim3(128), 0, stream>>>(
        x, Wih, Whh, bih, bhh, h0, c0, out, flags, hplane, lplane);
  }
}

// Round 4
// 4452.678 us; speedup vs baseline: 1.9974x; 1.0339x over previous
//
#include <hip/hip_runtime.h>
#include <hip/hip_bf16.h>

// Persistent-LSTM, round 4:
//   B=64,S=512,D=256,H=512. 4 teams x 16 batches; team = 64 WGs x 128 thr (2 waves).
//   Wave owns 16 gate rows (4 h-idx x 4 gates), W hi/lo bf16 resident in regs.
//   gates = [x_t,h_{t-1}] @ W^T via mfma_f32_16x16x32_bf16 (compensated hi/lo).
//   C/D layout (col=lane&15=batch, row=quad*4+reg) => lane-local LSTM cell.
//
//   ROUND 4 CHANGE: the x-projection is hoisted OUT of the 512-step lockstep
//   loop. Phase 1: each wave computes xpart = b + x_t @ Wih^T for its own
//   rows/batches/all t, stored fp32 in d_ws in per-lane layout (one dwordx4
//   per lane per step). No inter-phase barrier: each wave reads only its own
//   xproj (vmcnt(0) at the boundary for same-address RAW). Phase 2's step
//   loses the 16KB scattered cold-HBM x gather + 24 MFMAs + 256-elem bf16
//   repack that sat inside every step's serial chain (R3: 9.0 us/step with
//   all pipes <4% busy). xproj prefetched 1 step ahead -> zero exposed latency.
//   h-exchange: 512-deep ring (fresh addresses -> plain cached consumer loads,
//   no fences) + per-WG MAGIC-window flags, as R3. Fallback to R3 ring kernel
//   if ws_size < ~336 MB.

#define NB 64
#define NS 512
#define ND 256
#define NH 512
#define FLAG_MAGIC 0x41000000
#define PLANE_ELEMS (NB * NH)   // 32768 elems, 64 KiB/plane

typedef __bf16 bf16x8 __attribute__((ext_vector_type(8)));
typedef float  f32x4  __attribute__((ext_vector_type(4)));

union Frag {
  bf16x8 v;
  unsigned long long u[2];
  __bf16 e[8];
};

__device__ __forceinline__ float bf2f(__bf16 b) {
  unsigned short us = __builtin_bit_cast(unsigned short, b);
  unsigned int ui = ((unsigned int)us) << 16;
  return __builtin_bit_cast(float, ui);
}

__device__ __forceinline__ void hilo8(const float* vals, Frag& fh, Frag& fl) {
#pragma unroll
  for (int j = 0; j < 8; ++j) {
    __bf16 hi = (__bf16)vals[j];
    float r = vals[j] - bf2f(hi);
    fh.e[j] = hi;
    fl.e[j] = (__bf16)r;
  }
}

__device__ __forceinline__ float fsigmoid(float x) {
  return 1.0f / (1.0f + __expf(-x));
}
__device__ __forceinline__ float ftanh(float x) {
  float t = fminf(fmaxf(2.0f * x, -30.0f), 30.0f);
  float e = __expf(t);
  return (e - 1.0f) / (e + 1.0f);
}

// ---------------------------------------------------------------------------
// Round-4 kernel: precomputed x-projection + ring h-exchange
// ---------------------------------------------------------------------------
__global__ __launch_bounds__(128, 1)
void lstm_xp(const float* __restrict__ x,
             const float* __restrict__ Wih,
             const float* __restrict__ Whh,
             const float* __restrict__ bih,
             const float* __restrict__ bhh,
             const float* __restrict__ h0,
             const float* __restrict__ c0,
             float* __restrict__ out,
             int* __restrict__ flags,
             unsigned short* __restrict__ hring,   // [S][B][H] bf16-hi
             unsigned short* __restrict__ lring,   // [S][B][H] bf16-lo
             float4* __restrict__ xproj)           // [256*2][S][64] float4
{
  const int tid  = threadIdx.x;
  const int lane = tid & 63;
  const int wv   = tid >> 6;
  const int team = blockIdx.x >> 6;
  const int wg   = blockIdx.x & 63;
  const int l15  = lane & 15;
  const int quad = lane >> 4;
  const int hb   = wg * 8 + wv * 4;
  const int myb  = team * 16 + l15;
  const int myh  = hb + quad;

  int* flagsT = flags + team * 64;
  if (tid == 0)
    __hip_atomic_store(flagsT + wg, FLAG_MAGIC, __ATOMIC_RELAXED,
                       __HIP_MEMORY_SCOPE_AGENT);

  // persistent A operand: W rows, compensated hi/lo
  const int jA = l15 >> 2;
  const int gA = l15 & 3;
  const int rA = gA * NH + hb + jA;
  bf16x8 Ahi[24], Alo[24];
  {
    const float* wi = Wih + rA * ND;
    const float* wh = Whh + rA * NH;
#pragma unroll
    for (int c = 0; c < 24; ++c) {
      int k0 = c * 32 + quad * 8;
      const float* src = (c < 8) ? (wi + k0) : (wh + (k0 - 256));
      float4 f0 = *(const float4*)(src);
      float4 f1 = *(const float4*)(src + 4);
      float vals[8] = {f0.x, f0.y, f0.z, f0.w, f1.x, f1.y, f1.z, f1.w};
      Frag fh, fl;
      hilo8(vals, fh, fl);
      Ahi[c] = fh.v;
      Alo[c] = fl.v;
    }
  }

  float bias[4];
#pragma unroll
  for (int g = 0; g < 4; ++g)
    bias[g] = bih[g * NH + myh] + bhh[g * NH + myh];

  // ---- Phase 1: xpart(t) = bias + x_t @ Wih^T for own rows/batches --------
  float4* xpw = xproj + ((size_t)(blockIdx.x * 2 + wv)) * NS * 64;
#pragma unroll 1
  for (int t = 0; t < NS; ++t) {
    float4 xf[16];
    const float* xr = x + (myb * NS + t) * ND + quad * 8;
#pragma unroll
    for (int c = 0; c < 8; ++c) {
      xf[2 * c]     = *(const float4*)(xr + 32 * c);
      xf[2 * c + 1] = *(const float4*)(xr + 32 * c + 4);
    }
    f32x4 a_hh = {bias[0], bias[1], bias[2], bias[3]};
    f32x4 a_hl = {0.f, 0.f, 0.f, 0.f};
    f32x4 a_lh = {0.f, 0.f, 0.f, 0.f};
#pragma unroll
    for (int c = 0; c < 8; ++c) {
      float vals[8] = {xf[2*c].x, xf[2*c].y, xf[2*c].z, xf[2*c].w,
                       xf[2*c+1].x, xf[2*c+1].y, xf[2*c+1].z, xf[2*c+1].w};
      Frag bh, bl;
      hilo8(vals, bh, bl);
      a_hh = __builtin_amdgcn_mfma_f32_16x16x32_bf16(Ahi[c], bh.v, a_hh, 0, 0, 0);
      a_hl = __builtin_amdgcn_mfma_f32_16x16x32_bf16(Ahi[c], bl.v, a_hl, 0, 0, 0);
      a_lh = __builtin_amdgcn_mfma_f32_16x16x32_bf16(Alo[c], bh.v, a_lh, 0, 0, 0);
    }
    float4 xpv;
    xpv.x = a_hh[0] + a_hl[0] + a_lh[0];
    xpv.y = a_hh[1] + a_hl[1] + a_lh[1];
    xpv.z = a_hh[2] + a_hl[2] + a_lh[2];
    xpv.w = a_hh[3] + a_hl[3] + a_lh[3];
    xpw[t * 64 + lane] = xpv;   // coalesced 1 KB/wave
  }
  // same-address RAW safety: all xproj stores complete before phase-2 reads
  asm volatile("s_waitcnt vmcnt(0)" ::: "memory");

  // ---- Phase 2: recurrence ------------------------------------------------
  float c_st  = c0[myb * NH + myh];
  float h_val = 0.0f;
  float4 xp_cur = xpw[lane];   // t = 0 partial (L2-warm from phase 1)

#pragma unroll 1
  for (int t = 0; t < NS; ++t) {
    f32x4 a_hh = {0.f, 0.f, 0.f, 0.f};
    f32x4 a_hl = {0.f, 0.f, 0.f, 0.f};
    f32x4 a_lh = {0.f, 0.f, 0.f, 0.f};

    if (t > 0) {
      // wait for all 64 team WGs to finish step t-1
      while (true) {
        int fl = __hip_atomic_load(flagsT + lane, __ATOMIC_RELAXED,
                                   __HIP_MEMORY_SCOPE_AGENT);
        unsigned int d = (unsigned int)(fl - FLAG_MAGIC);
        if (__all(d >= (unsigned int)t && d <= 512u)) break;
        __builtin_amdgcn_s_sleep(1);
      }
      asm volatile("" ::: "memory");  // no h load hoisted above the poll

      // plain cached loads from plane t-1 (fresh addresses, L2-shareable)
      const unsigned short* hbp = hring + (t - 1) * PLANE_ELEMS + myb * NH + quad * 8;
      const unsigned short* lbp = lring + (t - 1) * PLANE_ELEMS + myb * NH + quad * 8;
#pragma unroll
      for (int c = 8; c < 24; ++c) {
        int off = 32 * (c - 8);
        Frag bh, bl;
        bh.v = *(const bf16x8*)(hbp + off);
        bl.v = *(const bf16x8*)(lbp + off);
        a_hh = __builtin_amdgcn_mfma_f32_16x16x32_bf16(Ahi[c], bh.v, a_hh, 0, 0, 0);
        a_hl = __builtin_amdgcn_mfma_f32_16x16x32_bf16(Ahi[c], bl.v, a_hl, 0, 0, 0);
        a_lh = __builtin_amdgcn_mfma_f32_16x16x32_bf16(Alo[c], bh.v, a_lh, 0, 0, 0);
      }
    } else {
      const float* hr = h0 + myb * NH + quad * 8;
#pragma unroll
      for (int c = 8; c < 24; ++c) {
        int off = 32 * (c - 8);
        float4 f0 = *(const float4*)(hr + off);
        float4 f1 = *(const float4*)(hr + off + 4);
        float vals[8] = {f0.x, f0.y, f0.z, f0.w, f1.x, f1.y, f1.z, f1.w};
        Frag bh, bl;
        hilo8(vals, bh, bl);
        a_hh = __builtin_amdgcn_mfma_f32_16x16x32_bf16(Ahi[c], bh.v, a_hh, 0, 0, 0);
        a_hl = __builtin_amdgcn_mfma_f32_16x16x32_bf16(Ahi[c], bl.v, a_hl, 0, 0, 0);
        a_lh = __builtin_amdgcn_mfma_f32_16x16x32_bf16(Alo[c], bh.v, a_lh, 0, 0, 0);
      }
    }

    // LSTM cell (lane-local); gate preact = precomputed xpart + h part
    float pre_i = xp_cur.x + a_hh[0] + a_hl[0] + a_lh[0];
    float pre_f = xp_cur.y + a_hh[1] + a_hl[1] + a_lh[1];
    float pre_g = xp_cur.z + a_hh[2] + a_hl[2] + a_lh[2];
    float pre_o = xp_cur.w + a_hh[3] + a_hl[3] + a_lh[3];
    float gi = fsigmoid(pre_i);
    float gf = fsigmoid(pre_f);
    float gg = ftanh(pre_g);
    float go = fsigmoid(pre_o);
    c_st  = gf * c_st + gi * gg;
    h_val = go * ftanh(c_st);

    // publish h_t (sc1 write-through to L3; packed u32 per h-pair)
    __bf16 hh = (__bf16)h_val;
    float  rr = h_val - bf2f(hh);
    __bf16 hl = (__bf16)rr;
    unsigned int uh = (unsigned int)__builtin_bit_cast(unsigned short, hh);
    unsigned int ul = (unsigned int)__builtin_bit_cast(unsigned short, hl);
    unsigned int ph = (unsigned int)__shfl_xor((int)uh, 16, 64);
    unsigned int pl = (unsigned int)__shfl_xor((int)ul, 16, 64);
    if ((quad & 1) == 0) {
      int eoff = t * PLANE_ELEMS + myb * NH + myh;
      __hip_atomic_store((unsigned int*)(hring + eoff), uh | (ph << 16),
                         __ATOMIC_RELAXED, __HIP_MEMORY_SCOPE_AGENT);
      __hip_atomic_store((unsigned int*)(lring + eoff), ul | (pl << 16),
                         __ATOMIC_RELAXED, __HIP_MEMORY_SCOPE_AGENT);
    }

    // order sc1 h stores before the flag
    asm volatile("s_waitcnt vmcnt(0)" ::: "memory");
    __syncthreads();
    if (tid == 0)
      __hip_atomic_store(flagsT + wg, FLAG_MAGIC + t + 1, __ATOMIC_RELAXED,
                         __HIP_MEMORY_SCOPE_AGENT);

    // off-critical-path stores/loads AFTER the flag:
    out[(myb * NS + t) * NH + myh] = h_val;        // embeddings
    if (t + 1 < NS) xp_cur = xpw[(t + 1) * 64 + lane];  // prefetch next xpart
  }

  const int obase = NB * NS * NH;
  out[obase + myb * NH + myh] = h_val;
  out[obase + NB * NH + myb * NH + myh] = c_st;
}

// ---------------------------------------------------------------------------
// Fallback: round-3 ring kernel (x-projection inside the loop)
// ---------------------------------------------------------------------------
__global__ __launch_bounds__(128, 1)
void lstm_ring(const float* __restrict__ x,
               const float* __restrict__ Wih,
               const float* __restrict__ Whh,
               const float* __restrict__ bih,
               const float* __restrict__ bhh,
               const float* __restrict__ h0,
               const float* __restrict__ c0,
               float* __restrict__ out,
               int* __restrict__ flags,
               unsigned short* __restrict__ hring,
               unsigned short* __restrict__ lring)
{
  const int tid  = threadIdx.x;
  const int lane = tid & 63;
  const int wv   = tid >> 6;
  const int team = blockIdx.x >> 6;
  const int wg   = blockIdx.x & 63;
  const int l15  = lane & 15;
  const int quad = lane >> 4;
  const int hb   = wg * 8 + wv * 4;
  const int myb  = team * 16 + l15;
  const int myh  = hb + quad;

  int* flagsT = flags + team * 64;
  if (tid == 0)
    __hip_atomic_store(flagsT + wg, FLAG_MAGIC, __ATOMIC_RELAXED,
                       __HIP_MEMORY_SCOPE_AGENT);

  const int jA = l15 >> 2;
  const int gA = l15 & 3;
  const int rA = gA * NH + hb + jA;
  bf16x8 Ahi[24], Alo[24];
  {
    const float* wi = Wih + rA * ND;
    const float* wh = Whh + rA * NH;
#pragma unroll
    for (int c = 0; c < 24; ++c) {
      int k0 = c * 32 + quad * 8;
      const float* src = (c < 8) ? (wi + k0) : (wh + (k0 - 256));
      float4 f0 = *(const float4*)(src);
      float4 f1 = *(const float4*)(src + 4);
      float vals[8] = {f0.x, f0.y, f0.z, f0.w, f1.x, f1.y, f1.z, f1.w};
      Frag fh, fl;
      hilo8(vals, fh, fl);
      Ahi[c] = fh.v;
      Alo[c] = fl.v;
    }
  }

  float bias[4];
#pragma unroll
  for (int g = 0; g < 4; ++g)
    bias[g] = bih[g * NH + myh] + bhh[g * NH + myh];

  float c_st  = c0[myb * NH + myh];
  float h_val = 0.0f;

#pragma unroll 1
  for (int t = 0; t < NS; ++t) {
    float4 xf[16];
    const float* xr = x + (myb * NS + t) * ND + quad * 8;
#pragma unroll
    for (int c = 0; c < 8; ++c) {
      xf[2 * c]     = *(const float4*)(xr + 32 * c);
      xf[2 * c + 1] = *(const float4*)(xr + 32 * c + 4);
    }

    f32x4 a_hh = {bias[0], bias[1], bias[2], bias[3]};
    f32x4 a_hl = {0.f, 0.f, 0.f, 0.f};
    f32x4 a_lh = {0.f, 0.f, 0.f, 0.f};

#pragma unroll
    for (int c = 0; c < 8; ++c) {
      float vals[8] = {xf[2*c].x, xf[2*c].y, xf[2*c].z, xf[2*c].w,
                       xf[2*c+1].x, xf[2*c+1].y, xf[2*c+1].z, xf[2*c+1].w};
      Frag bh, bl;
      hilo8(vals, bh, bl);
      a_hh = __builtin_amdgcn_mfma_f32_16x16x32_bf16(Ahi[c], bh.v, a_hh, 0, 0, 0);
      a_hl = __builtin_amdgcn_mfma_f32_16x16x32_bf16(Ahi[c], bl.v, a_hl, 0, 0, 0);
      a_lh = __builtin_amdgcn_mfma_f32_16x16x32_bf16(Alo[c], bh.v, a_lh, 0, 0, 0);
    }

    if (t > 0) {
      while (true) {
        int fl = __hip_atomic_load(flagsT + lane, __ATOMIC_RELAXED,
                                   __HIP_MEMORY_SCOPE_AGENT);
        unsigned int d = (unsigned int)(fl - FLAG_MAGIC);
        if (__all(d >= (unsigned int)t && d <= 512u)) break;
        __builtin_amdgcn_s_sleep(1);
      }
      asm volatile("" ::: "memory");

      const unsigned short* hbp = hring + (t - 1) * PLANE_ELEMS + myb * NH + quad * 8;
      const unsigned short* lbp = lring + (t - 1) * PLANE_ELEMS + myb * NH + quad * 8;
#pragma unroll
      for (int c = 8; c < 24; ++c) {
        int off = 32 * (c - 8);
        Frag bh, bl;
        bh.v = *(const bf16x8*)(hbp + off);
        bl.v = *(const bf16x8*)(lbp + off);
        a_hh = __builtin_amdgcn_mfma_f32_16x16x32_bf16(Ahi[c], bh.v, a_hh, 0, 0, 0);
        a_hl = __builtin_amdgcn_mfma_f32_16x16x32_bf16(Ahi[c], bl.v, a_hl, 0, 0, 0);
        a_lh = __builtin_amdgcn_mfma_f32_16x16x32_bf16(Alo[c], bh.v, a_lh, 0, 0, 0);
      }
    } else {
      const float* hr = h0 + myb * NH + quad * 8;
#pragma unroll
      for (int c = 8; c < 24; ++c) {
        int off = 32 * (c - 8);
        float4 f0 = *(const float4*)(hr + off);
        float4 f1 = *(const float4*)(hr + off + 4);
        float vals[8] = {f0.x, f0.y, f0.z, f0.w, f1.x, f1.y, f1.z, f1.w};
        Frag bh, bl;
        hilo8(vals, bh, bl);
        a_hh = __builtin_amdgcn_mfma_f32_16x16x32_bf16(Ahi[c], bh.v, a_hh, 0, 0, 0);
        a_hl = __builtin_amdgcn_mfma_f32_16x16x32_bf16(Ahi[c], bl.v, a_hl, 0, 0, 0);
        a_lh = __builtin_amdgcn_mfma_f32_16x16x32_bf16(Alo[c], bh.v, a_lh, 0, 0, 0);
      }
    }

    float pre_i = a_hh[0] + a_hl[0] + a_lh[0];
    float pre_f = a_hh[1] + a_hl[1] + a_lh[1];
    float pre_g = a_hh[2] + a_hl[2] + a_lh[2];
    float pre_o = a_hh[3] + a_hl[3] + a_lh[3];
    float gi = fsigmoid(pre_i);
    float gf = fsigmoid(pre_f);
    float gg = ftanh(pre_g);
    float go = fsigmoid(pre_o);
    c_st  = gf * c_st + gi * gg;
    h_val = go * ftanh(c_st);

    __bf16 hh = (__bf16)h_val;
    float  rr = h_val - bf2f(hh);
    __bf16 hl = (__bf16)rr;
    unsigned int uh = (unsigned int)__builtin_bit_cast(unsigned short, hh);
    unsigned int ul = (unsigned int)__builtin_bit_cast(unsigned short, hl);
    unsigned int ph = (unsigned int)__shfl_xor((int)uh, 16, 64);
    unsigned int pl = (unsigned int)__shfl_xor((int)ul, 16, 64);
    if ((quad & 1) == 0) {
      int eoff = t * PLANE_ELEMS + myb * NH + myh;
      __hip_atomic_store((unsigned int*)(hring + eoff), uh | (ph << 16),
                         __ATOMIC_RELAXED, __HIP_MEMORY_SCOPE_AGENT);
      __hip_atomic_store((unsigned int*)(lring + eoff), ul | (pl << 16),
                         __ATOMIC_RELAXED, __HIP_MEMORY_SCOPE_AGENT);
    }

    asm volatile("s_waitcnt vmcnt(0)" ::: "memory");
    __syncthreads();
    if (tid == 0)
      __hip_atomic_store(flagsT + wg, FLAG_MAGIC + t + 1, __ATOMIC_RELAXED,
                         __HIP_MEMORY_SCOPE_AGENT);

    out[(myb * NS + t) * NH + myh] = h_val;
  }

  const int obase = NB * NS * NH;
  out[obase + myb * NH + myh] = h_val;
  out[obase + NB * NH + myb * NH + myh] = c_st;
}

extern "C" void kernel_launch(void* const* d_in, const int* in_sizes, int n_in,
                              void* d_out, int out_size, void* d_ws, size_t ws_size,
                              hipStream_t stream) {
  const float* x   = (const float*)d_in[0];
  const float* Wih = (const float*)d_in[1];
  const float* Whh = (const float*)d_in[2];
  const float* bih = (const float*)d_in[3];
  const float* bhh = (const float*)d_in[4];
  const float* h0  = (const float*)d_in[5];
  const float* c0  = (const float*)d_in[6];
  float* out = (float*)d_out;

  char* ws = (char*)d_ws;
  int* flags = (int*)ws;  // 1 KiB used; rings at +4096

  const size_t ringBytes  = (size_t)NS * PLANE_ELEMS * sizeof(unsigned short); // 33.5 MB
  const size_t xprojBytes = (size_t)512 * NS * 64 * sizeof(float4);            // 268.4 MB
  const size_t need_ring  = 4096 + 2 * ringBytes;               // ~67.1 MB
  const size_t need_full  = need_ring + xprojBytes;             // ~335.6 MB

  unsigned short* hring = (unsigned short*)(ws + 4096);
  unsigned short* lring = (unsigned short*)(ws + 4096 + ringBytes);

  if (ws_size >= need_full) {
    float4* xproj = (float4*)(ws + need_ring);
    lstm_xp<<<dim3(256), dim3(128), 0, stream>>>(
        x, Wih, Whh, bih, bhh, h0, c0, out, flags, hring, lring, xproj);
  } else {
    lstm_ring<<<dim3(256), dim3(128), 0, stream>>>(
        x, Wih, Whh, bih, bhh, h0, c0, out, flags, hring, lring);
  }
}